// Round 2
// baseline (289.738 us; speedup 1.0000x reference)
//
#include <hip/hip_runtime.h>
#include <math.h>

// Problem constants (B derived at launch; spatial dims fixed by weight shapes).
#define HH 1024
#define WW 1024
#define N1 262144   // 512*512 per-image level-1 detail size
#define N2 65536    // 256*256
#define N3 16384    // 128*128

#define C_INV_SQRT2 0.70710678118654752440f

static __device__ __forceinline__ void haar_fwd(float P, float Q, float R, float S,
                                                float& a, float& h, float& v, float& d) {
    // reference: split along -1 (cols) first, then -2 (rows)
    const float C = C_INV_SQRT2;
    float lo0 = (P + Q) * C, lo1 = (R + S) * C;
    float hi0 = (P - Q) * C, hi1 = (R - S) * C;
    a = (lo0 + lo1) * C; h = (lo0 - lo1) * C;
    v = (hi0 + hi1) * C; d = (hi0 - hi1) * C;
}

static __device__ __forceinline__ void haar_inv(float a, float h, float v, float d,
                                                float& P, float& Q, float& R, float& S) {
    // reference: merge along -2 (rows) first, then -1 (cols)
    const float C = C_INV_SQRT2;
    float elo = (a + h) * C, olo = (a - h) * C;
    float ehi = (v + d) * C, ohi = (v - d) * C;
    P = (elo + ehi) * C; Q = (elo - ehi) * C;
    R = (olo + ohi) * C; S = (olo - ohi) * C;
}

// ---------------------------------------------------------------------------
// Kernel 1: forward DWT (registers only) + dot-product logit accumulation.
// Grid: (W/64, H/64, B); 64 threads (1 wave); thread = one 8x8 input block.
// 64-thread blocks: 4096 blocks total -> ~16 waves/CU resident (latency hiding);
// wave-only reduction (no LDS round-trip).
// logits layout per batch: [0]=approx gate logit, [1..3]=level3 (Wd1 coarsest),
// [4..6]=level2 (Wd2), [7..9]=level1 (Wd3 finest).
// ---------------------------------------------------------------------------
__global__ __launch_bounds__(64) void wa_fwd_dots(
    const float* __restrict__ x,
    const float* __restrict__ Wa,
    const float* __restrict__ Wd1,   // [3*N3, 3] coarsest
    const float* __restrict__ Wd2,   // [3*N2, 3]
    const float* __restrict__ Wd3,   // [3*N1, 3] finest
    float* __restrict__ logits)
{
    const int b = blockIdx.z;
    const int t = threadIdx.x;
    const int tr = t >> 3, tc = t & 7;             // 8x8 threads of 8x8 pixels -> 64x64 tile
    const int y0 = blockIdx.y * 64 + tr * 8;
    const int x0 = blockIdx.x * 64 + tc * 8;

    const float* xb = x + (size_t)b * HH * WW;

    float p[8][8];
    #pragma unroll
    for (int r = 0; r < 8; ++r) {
        const float4* row = (const float4*)(xb + (size_t)(y0 + r) * WW + x0);
        float4 u0 = row[0], u1 = row[1];
        p[r][0] = u0.x; p[r][1] = u0.y; p[r][2] = u0.z; p[r][3] = u0.w;
        p[r][4] = u1.x; p[r][5] = u1.y; p[r][6] = u1.z; p[r][7] = u1.w;
    }

    float acc[10];
    #pragma unroll
    for (int k = 0; k < 10; ++k) acc[k] = 0.f;

    // Level 1 (finest): 4x4 coefficients. Weight rows for the 4 consecutive j's
    // are 12 contiguous floats per stream (h/v/d) -> 3 float4 loads each.
    float a1[4][4];
    #pragma unroll
    for (int i = 0; i < 4; ++i) {
        const size_t jj0 = (size_t)((y0 >> 1) + i) * 512 + (size_t)(x0 >> 1);
        float wh[12], wv[12], wd[12];
        {
            const float4* H = (const float4*)(Wd3 + jj0 * 3);                       // 48B-aligned
            const float4* V = (const float4*)(Wd3 + (jj0 + (size_t)N1) * 3);
            const float4* D = (const float4*)(Wd3 + (jj0 + (size_t)2 * N1) * 3);
            #pragma unroll
            for (int q = 0; q < 3; ++q) {
                float4 a = H[q]; wh[4*q] = a.x; wh[4*q+1] = a.y; wh[4*q+2] = a.z; wh[4*q+3] = a.w;
                float4 c = V[q]; wv[4*q] = c.x; wv[4*q+1] = c.y; wv[4*q+2] = c.z; wv[4*q+3] = c.w;
                float4 e = D[q]; wd[4*q] = e.x; wd[4*q+1] = e.y; wd[4*q+2] = e.z; wd[4*q+3] = e.w;
            }
        }
        #pragma unroll
        for (int j = 0; j < 4; ++j) {
            float a, h, v, d;
            haar_fwd(p[2*i][2*j], p[2*i][2*j+1], p[2*i+1][2*j], p[2*i+1][2*j+1], a, h, v, d);
            a1[i][j] = a;
            #pragma unroll
            for (int c = 0; c < 3; ++c)
                acc[7 + c] += h * wh[j*3 + c] + v * wv[j*3 + c] + d * wd[j*3 + c];
        }
    }

    // Level 2: 2x2 coefficients. 6 contiguous floats per stream -> 3 float2 loads.
    float a2[2][2];
    #pragma unroll
    for (int i = 0; i < 2; ++i) {
        const size_t jj0 = (size_t)((y0 >> 2) + i) * 256 + (size_t)(x0 >> 2);
        float wh[6], wv[6], wd[6];
        {
            const float2* H = (const float2*)(Wd2 + jj0 * 3);                       // 24B-aligned
            const float2* V = (const float2*)(Wd2 + (jj0 + (size_t)N2) * 3);
            const float2* D = (const float2*)(Wd2 + (jj0 + (size_t)2 * N2) * 3);
            #pragma unroll
            for (int q = 0; q < 3; ++q) {
                float2 a = H[q]; wh[2*q] = a.x; wh[2*q+1] = a.y;
                float2 c = V[q]; wv[2*q] = c.x; wv[2*q+1] = c.y;
                float2 e = D[q]; wd[2*q] = e.x; wd[2*q+1] = e.y;
            }
        }
        #pragma unroll
        for (int j = 0; j < 2; ++j) {
            float a, h, v, d;
            haar_fwd(a1[2*i][2*j], a1[2*i][2*j+1], a1[2*i+1][2*j], a1[2*i+1][2*j+1], a, h, v, d);
            a2[i][j] = a;
            #pragma unroll
            for (int c = 0; c < 3; ++c)
                acc[4 + c] += h * wh[j*3 + c] + v * wv[j*3 + c] + d * wd[j*3 + c];
        }
    }

    // Level 3 (coarsest): one coefficient set; approx-gate dot + Wd1 columns.
    {
        float a, h, v, d;
        haar_fwd(a2[0][0], a2[0][1], a2[1][0], a2[1][1], a, h, v, d);
        const size_t jj = (size_t)(y0 >> 3) * 128 + (size_t)(x0 >> 3);
        acc[0] += a * Wa[jj];
        const float* wh = Wd1 + jj * 3;
        const float* wv = Wd1 + (jj + (size_t)N3) * 3;
        const float* wd = Wd1 + (jj + (size_t)2 * N3) * 3;
        #pragma unroll
        for (int c = 0; c < 3; ++c)
            acc[1 + c] += h * wh[c] + v * wv[c] + d * wd[c];
    }

    // Single-wave butterfly reduction, then lane 0 issues the 10 atomics.
    #pragma unroll
    for (int k = 0; k < 10; ++k) {
        float s = acc[k];
        #pragma unroll
        for (int off = 32; off > 0; off >>= 1) s += __shfl_down(s, off, 64);
        acc[k] = s;
    }
    if (t == 0) {
        #pragma unroll
        for (int k = 0; k < 10; ++k)
            atomicAdd(&logits[b * 10 + k], acc[k]);
    }
}

// ---------------------------------------------------------------------------
// Kernel 2: recompute coefficients from x, compute gates in-block from logits,
// gate, inverse-DWT, write output. Grid: (W/64, H/64, B); 64 threads.
// gates layout: [0]=sigmoid approx, [1..3]=softmax lvl3, [4..6]=lvl2, [7..9]=lvl1.
// ---------------------------------------------------------------------------
__global__ __launch_bounds__(64) void wa_recon(
    const float* __restrict__ x,
    const float* __restrict__ logits,
    const float* __restrict__ ba,
    const float* __restrict__ bd1,
    const float* __restrict__ bd2,
    const float* __restrict__ bd3,
    float* __restrict__ out)
{
    const int b = blockIdx.z;
    const int t = threadIdx.x;

    // Gates computed redundantly per block (10 loads + 4 exp — noise).
    __shared__ float g[10];
    if (t < 10) {
        const float* L = logits + b * 10;
        float val;
        if (t == 0) {
            val = 1.f / (1.f + expf(-(L[0] + ba[0])));
        } else {
            const int grp = (t - 1) / 3;            // 0: lvl3(bd1), 1: lvl2(bd2), 2: lvl1(bd3)
            const int idx = (t - 1) - grp * 3;
            const float* bd = (grp == 0) ? bd1 : (grp == 1) ? bd2 : bd3;
            const float l0 = L[1 + 3*grp + 0] + bd[0];
            const float l1 = L[1 + 3*grp + 1] + bd[1];
            const float l2 = L[1 + 3*grp + 2] + bd[2];
            const float m  = fmaxf(l0, fmaxf(l1, l2));
            const float e0 = expf(l0 - m), e1 = expf(l1 - m), e2 = expf(l2 - m);
            const float li = (idx == 0) ? l0 : (idx == 1) ? l1 : l2;
            val = expf(li - m) / (e0 + e1 + e2);
        }
        g[t] = val;
    }
    __syncthreads();

    const int tr = t >> 3, tc = t & 7;
    const int y0 = blockIdx.y * 64 + tr * 8;
    const int x0 = blockIdx.x * 64 + tc * 8;

    const float* xb = x + (size_t)b * HH * WW;

    float p[8][8];
    #pragma unroll
    for (int r = 0; r < 8; ++r) {
        const float4* row = (const float4*)(xb + (size_t)(y0 + r) * WW + x0);
        float4 u0 = row[0], u1 = row[1];
        p[r][0] = u0.x; p[r][1] = u0.y; p[r][2] = u0.z; p[r][3] = u0.w;
        p[r][4] = u1.x; p[r][5] = u1.y; p[r][6] = u1.z; p[r][7] = u1.w;
    }

    // Forward DWT, keeping all coefficients.
    float a1[4][4], h1[4][4], v1[4][4], d1[4][4];
    #pragma unroll
    for (int i = 0; i < 4; ++i)
        #pragma unroll
        for (int j = 0; j < 4; ++j)
            haar_fwd(p[2*i][2*j], p[2*i][2*j+1], p[2*i+1][2*j], p[2*i+1][2*j+1],
                     a1[i][j], h1[i][j], v1[i][j], d1[i][j]);

    float a2[2][2], h2[2][2], v2[2][2], d2[2][2];
    #pragma unroll
    for (int i = 0; i < 2; ++i)
        #pragma unroll
        for (int j = 0; j < 2; ++j)
            haar_fwd(a1[2*i][2*j], a1[2*i][2*j+1], a1[2*i+1][2*j], a1[2*i+1][2*j+1],
                     a2[i][j], h2[i][j], v2[i][j], d2[i][j]);

    float a3, h3, v3, d3;
    haar_fwd(a2[0][0], a2[0][1], a2[1][0], a2[1][1], a3, h3, v3, d3);

    // Gate + inverse.
    a3 *= g[0];
    float r2[2][2];
    haar_inv(a3, h3 * g[1], v3 * g[2], d3 * g[3],
             r2[0][0], r2[0][1], r2[1][0], r2[1][1]);

    float r1[4][4];
    #pragma unroll
    for (int i = 0; i < 2; ++i)
        #pragma unroll
        for (int j = 0; j < 2; ++j)
            haar_inv(r2[i][j], h2[i][j] * g[4], v2[i][j] * g[5], d2[i][j] * g[6],
                     r1[2*i][2*j], r1[2*i][2*j+1], r1[2*i+1][2*j], r1[2*i+1][2*j+1]);

    float r0[8][8];
    #pragma unroll
    for (int i = 0; i < 4; ++i)
        #pragma unroll
        for (int j = 0; j < 4; ++j)
            haar_inv(r1[i][j], h1[i][j] * g[7], v1[i][j] * g[8], d1[i][j] * g[9],
                     r0[2*i][2*j], r0[2*i][2*j+1], r0[2*i+1][2*j], r0[2*i+1][2*j+1]);

    float* ob = out + (size_t)b * HH * WW;
    #pragma unroll
    for (int r = 0; r < 8; ++r) {
        float4* row = (float4*)(ob + (size_t)(y0 + r) * WW + x0);
        float4 u0, u1;
        u0.x = r0[r][0]; u0.y = r0[r][1]; u0.z = r0[r][2]; u0.w = r0[r][3];
        u1.x = r0[r][4]; u1.y = r0[r][5]; u1.z = r0[r][6]; u1.w = r0[r][7];
        row[0] = u0; row[1] = u1;
    }
}

extern "C" void kernel_launch(void* const* d_in, const int* in_sizes, int n_in,
                              void* d_out, int out_size, void* d_ws, size_t ws_size,
                              hipStream_t stream) {
    const float* x   = (const float*)d_in[0];
    const float* Wa  = (const float*)d_in[1];
    const float* ba  = (const float*)d_in[2];
    const float* Wd1 = (const float*)d_in[3];
    const float* bd1 = (const float*)d_in[4];
    const float* Wd2 = (const float*)d_in[5];
    const float* bd2 = (const float*)d_in[6];
    const float* Wd3 = (const float*)d_in[7];
    const float* bd3 = (const float*)d_in[8];
    float* out = (float*)d_out;

    const int B = in_sizes[0] / (HH * WW);

    float* logits = (float*)d_ws;          // [B,10], zeroed every launch
    hipMemsetAsync(logits, 0, (size_t)B * 10 * sizeof(float), stream);

    dim3 grid(WW / 64, HH / 64, B);
    wa_fwd_dots<<<grid, 64, 0, stream>>>(x, Wa, Wd1, Wd2, Wd3, logits);
    wa_recon<<<grid, 64, 0, stream>>>(x, logits, ba, bd1, bd2, bd3, out);
}

// Round 3
// 172.693 us; speedup vs baseline: 1.6778x; 1.6778x over previous
//
#include <hip/hip_runtime.h>
#include <math.h>

// Problem constants (B derived at launch; spatial dims fixed by weight shapes).
#define HH 1024
#define WW 1024
#define N1 262144   // 512*512 per-image level-1 detail size
#define N2 65536    // 256*256
#define N3 16384    // 128*128
#define BLOCKS_PER_B 64   // fwd grid: (8,8,B) -> 64 partial rows per batch

#define C_INV_SQRT2 0.70710678118654752440f

static __device__ __forceinline__ void haar_fwd(float P, float Q, float R, float S,
                                                float& a, float& h, float& v, float& d) {
    // reference: split along -1 (cols) first, then -2 (rows)
    const float C = C_INV_SQRT2;
    float lo0 = (P + Q) * C, lo1 = (R + S) * C;
    float hi0 = (P - Q) * C, hi1 = (R - S) * C;
    a = (lo0 + lo1) * C; h = (lo0 - lo1) * C;
    v = (hi0 + hi1) * C; d = (hi0 - hi1) * C;
}

static __device__ __forceinline__ void haar_inv(float a, float h, float v, float d,
                                                float& P, float& Q, float& R, float& S) {
    // reference: merge along -2 (rows) first, then -1 (cols)
    const float C = C_INV_SQRT2;
    float elo = (a + h) * C, olo = (a - h) * C;
    float ehi = (v + d) * C, ohi = (v - d) * C;
    P = (elo + ehi) * C; Q = (elo - ehi) * C;
    R = (olo + ohi) * C; S = (olo - ohi) * C;
}

// ---------------------------------------------------------------------------
// Kernel 1: forward DWT (registers only) + dot-product logit partials.
// Grid: (8, 8, B); 256 threads; thread = one 8x8 input block (128x128 tile/block).
// NO atomics: each block writes one 10-float partial row to ws.
// partial row layout: [0]=approx logit, [1..3]=lvl3 (Wd1), [4..6]=lvl2 (Wd2),
// [7..9]=lvl1 (Wd3).
// ---------------------------------------------------------------------------
__global__ __launch_bounds__(256) void wa_fwd_dots(
    const float* __restrict__ x,
    const float* __restrict__ Wa,
    const float* __restrict__ Wd1,   // [3*N3, 3] coarsest
    const float* __restrict__ Wd2,   // [3*N2, 3]
    const float* __restrict__ Wd3,   // [3*N1, 3] finest
    float* __restrict__ partial)     // [B * BLOCKS_PER_B, 10]
{
    const int b = blockIdx.z;
    const int t = threadIdx.x;
    const int tr = t >> 4, tc = t & 15;            // 16x16 threads of 8x8 px
    const int y0 = blockIdx.y * 128 + tr * 8;
    const int x0 = blockIdx.x * 128 + tc * 8;

    const float* xb = x + (size_t)b * HH * WW;

    float p[8][8];
    #pragma unroll
    for (int r = 0; r < 8; ++r) {
        const float4* row = (const float4*)(xb + (size_t)(y0 + r) * WW + x0);
        float4 u0 = row[0], u1 = row[1];
        p[r][0] = u0.x; p[r][1] = u0.y; p[r][2] = u0.z; p[r][3] = u0.w;
        p[r][4] = u1.x; p[r][5] = u1.y; p[r][6] = u1.z; p[r][7] = u1.w;
    }

    float acc[10];
    #pragma unroll
    for (int k = 0; k < 10; ++k) acc[k] = 0.f;

    // Level 1 (finest): 4x4 coefficients. 12 contiguous weight floats per
    // stream per row -> 3 float4 loads each (48B-aligned since x0%8==0).
    float a1[4][4];
    #pragma unroll
    for (int i = 0; i < 4; ++i) {
        const size_t jj0 = (size_t)((y0 >> 1) + i) * 512 + (size_t)(x0 >> 1);
        float wh[12], wv[12], wd[12];
        {
            const float4* H = (const float4*)(Wd3 + jj0 * 3);
            const float4* V = (const float4*)(Wd3 + (jj0 + (size_t)N1) * 3);
            const float4* D = (const float4*)(Wd3 + (jj0 + (size_t)2 * N1) * 3);
            #pragma unroll
            for (int q = 0; q < 3; ++q) {
                float4 a = H[q]; wh[4*q] = a.x; wh[4*q+1] = a.y; wh[4*q+2] = a.z; wh[4*q+3] = a.w;
                float4 c = V[q]; wv[4*q] = c.x; wv[4*q+1] = c.y; wv[4*q+2] = c.z; wv[4*q+3] = c.w;
                float4 e = D[q]; wd[4*q] = e.x; wd[4*q+1] = e.y; wd[4*q+2] = e.z; wd[4*q+3] = e.w;
            }
        }
        #pragma unroll
        for (int j = 0; j < 4; ++j) {
            float a, h, v, d;
            haar_fwd(p[2*i][2*j], p[2*i][2*j+1], p[2*i+1][2*j], p[2*i+1][2*j+1], a, h, v, d);
            a1[i][j] = a;
            #pragma unroll
            for (int c = 0; c < 3; ++c)
                acc[7 + c] += h * wh[j*3 + c] + v * wv[j*3 + c] + d * wd[j*3 + c];
        }
    }

    // Level 2: 2x2 coefficients. 6 contiguous floats per stream -> 3 float2 loads.
    float a2[2][2];
    #pragma unroll
    for (int i = 0; i < 2; ++i) {
        const size_t jj0 = (size_t)((y0 >> 2) + i) * 256 + (size_t)(x0 >> 2);
        float wh[6], wv[6], wd[6];
        {
            const float2* H = (const float2*)(Wd2 + jj0 * 3);
            const float2* V = (const float2*)(Wd2 + (jj0 + (size_t)N2) * 3);
            const float2* D = (const float2*)(Wd2 + (jj0 + (size_t)2 * N2) * 3);
            #pragma unroll
            for (int q = 0; q < 3; ++q) {
                float2 a = H[q]; wh[2*q] = a.x; wh[2*q+1] = a.y;
                float2 c = V[q]; wv[2*q] = c.x; wv[2*q+1] = c.y;
                float2 e = D[q]; wd[2*q] = e.x; wd[2*q+1] = e.y;
            }
        }
        #pragma unroll
        for (int j = 0; j < 2; ++j) {
            float a, h, v, d;
            haar_fwd(a1[2*i][2*j], a1[2*i][2*j+1], a1[2*i+1][2*j], a1[2*i+1][2*j+1], a, h, v, d);
            a2[i][j] = a;
            #pragma unroll
            for (int c = 0; c < 3; ++c)
                acc[4 + c] += h * wh[j*3 + c] + v * wv[j*3 + c] + d * wd[j*3 + c];
        }
    }

    // Level 3 (coarsest): one coefficient set; approx-gate dot + Wd1 columns.
    {
        float a, h, v, d;
        haar_fwd(a2[0][0], a2[0][1], a2[1][0], a2[1][1], a, h, v, d);
        const size_t jj = (size_t)(y0 >> 3) * 128 + (size_t)(x0 >> 3);
        acc[0] += a * Wa[jj];
        const float* wh = Wd1 + jj * 3;
        const float* wv = Wd1 + (jj + (size_t)N3) * 3;
        const float* wd = Wd1 + (jj + (size_t)2 * N3) * 3;
        #pragma unroll
        for (int c = 0; c < 3; ++c)
            acc[1 + c] += h * wh[c] + v * wv[c] + d * wd[c];
    }

    // Block reduction: wave butterfly -> LDS across 4 waves -> single 10-float
    // partial-row store. No atomics.
    #pragma unroll
    for (int k = 0; k < 10; ++k) {
        float s = acc[k];
        #pragma unroll
        for (int off = 32; off > 0; off >>= 1) s += __shfl_down(s, off, 64);
        acc[k] = s;
    }
    __shared__ float red[4][10];
    const int lane = t & 63, wave = t >> 6;
    if (lane == 0) {
        #pragma unroll
        for (int k = 0; k < 10; ++k) red[wave][k] = acc[k];
    }
    __syncthreads();
    if (t < 10) {
        const int blkflat = b * BLOCKS_PER_B + blockIdx.y * 8 + blockIdx.x;
        partial[(size_t)blkflat * 10 + t] = red[0][t] + red[1][t] + red[2][t] + red[3][t];
    }
}

// ---------------------------------------------------------------------------
// Kernel 2: reduce 64 partial rows per batch, apply biases, sigmoid/softmax.
// Grid: (B); 64 threads (one wave). gates layout per batch:
// [0]=sigmoid approx, [1..3]=softmax lvl3, [4..6]=lvl2, [7..9]=lvl1.
// ---------------------------------------------------------------------------
__global__ __launch_bounds__(64) void wa_gates(
    const float* __restrict__ partial,
    const float* __restrict__ ba,
    const float* __restrict__ bd1,
    const float* __restrict__ bd2,
    const float* __restrict__ bd3,
    float* __restrict__ gates)
{
    const int b = blockIdx.x;
    const int l = threadIdx.x;
    const float* row = partial + (size_t)(b * BLOCKS_PER_B + l) * 10;
    float v[10];
    #pragma unroll
    for (int k = 0; k < 10; ++k) v[k] = row[k];
    #pragma unroll
    for (int k = 0; k < 10; ++k) {
        #pragma unroll
        for (int off = 32; off > 0; off >>= 1) v[k] += __shfl_down(v[k], off, 64);
    }
    if (l == 0) {
        float* G = gates + b * 10;
        G[0] = 1.f / (1.f + expf(-(v[0] + ba[0])));
        const float* bds[3] = { bd1, bd2, bd3 };
        #pragma unroll
        for (int lv = 0; lv < 3; ++lv) {
            float l0 = v[1 + 3*lv + 0] + bds[lv][0];
            float l1 = v[1 + 3*lv + 1] + bds[lv][1];
            float l2 = v[1 + 3*lv + 2] + bds[lv][2];
            float m = fmaxf(l0, fmaxf(l1, l2));
            float e0 = expf(l0 - m), e1 = expf(l1 - m), e2 = expf(l2 - m);
            float inv = 1.f / (e0 + e1 + e2);
            G[1 + 3*lv + 0] = e0 * inv;
            G[1 + 3*lv + 1] = e1 * inv;
            G[1 + 3*lv + 2] = e2 * inv;
        }
    }
}

// ---------------------------------------------------------------------------
// Kernel 3: recompute coefficients from x, gate, inverse-DWT, write output.
// Grid: (16, 16, B); 64 threads; thread = one 8x8 block (64x64 tile/block).
// ---------------------------------------------------------------------------
__global__ __launch_bounds__(64) void wa_recon(
    const float* __restrict__ x,
    const float* __restrict__ gates,
    float* __restrict__ out)
{
    const int b = blockIdx.z;
    const int t = threadIdx.x;

    __shared__ float g[10];
    if (t < 10) g[t] = gates[b * 10 + t];
    __syncthreads();

    const int tr = t >> 3, tc = t & 7;
    const int y0 = blockIdx.y * 64 + tr * 8;
    const int x0 = blockIdx.x * 64 + tc * 8;

    const float* xb = x + (size_t)b * HH * WW;

    float p[8][8];
    #pragma unroll
    for (int r = 0; r < 8; ++r) {
        const float4* row = (const float4*)(xb + (size_t)(y0 + r) * WW + x0);
        float4 u0 = row[0], u1 = row[1];
        p[r][0] = u0.x; p[r][1] = u0.y; p[r][2] = u0.z; p[r][3] = u0.w;
        p[r][4] = u1.x; p[r][5] = u1.y; p[r][6] = u1.z; p[r][7] = u1.w;
    }

    // Forward DWT, keeping all coefficients.
    float a1[4][4], h1[4][4], v1[4][4], d1[4][4];
    #pragma unroll
    for (int i = 0; i < 4; ++i)
        #pragma unroll
        for (int j = 0; j < 4; ++j)
            haar_fwd(p[2*i][2*j], p[2*i][2*j+1], p[2*i+1][2*j], p[2*i+1][2*j+1],
                     a1[i][j], h1[i][j], v1[i][j], d1[i][j]);

    float a2[2][2], h2[2][2], v2[2][2], d2[2][2];
    #pragma unroll
    for (int i = 0; i < 2; ++i)
        #pragma unroll
        for (int j = 0; j < 2; ++j)
            haar_fwd(a1[2*i][2*j], a1[2*i][2*j+1], a1[2*i+1][2*j], a1[2*i+1][2*j+1],
                     a2[i][j], h2[i][j], v2[i][j], d2[i][j]);

    float a3, h3, v3, d3;
    haar_fwd(a2[0][0], a2[0][1], a2[1][0], a2[1][1], a3, h3, v3, d3);

    // Gate + inverse.
    a3 *= g[0];
    float r2[2][2];
    haar_inv(a3, h3 * g[1], v3 * g[2], d3 * g[3],
             r2[0][0], r2[0][1], r2[1][0], r2[1][1]);

    float r1[4][4];
    #pragma unroll
    for (int i = 0; i < 2; ++i)
        #pragma unroll
        for (int j = 0; j < 2; ++j)
            haar_inv(r2[i][j], h2[i][j] * g[4], v2[i][j] * g[5], d2[i][j] * g[6],
                     r1[2*i][2*j], r1[2*i][2*j+1], r1[2*i+1][2*j], r1[2*i+1][2*j+1]);

    float r0[8][8];
    #pragma unroll
    for (int i = 0; i < 4; ++i)
        #pragma unroll
        for (int j = 0; j < 4; ++j)
            haar_inv(r1[i][j], h1[i][j] * g[7], v1[i][j] * g[8], d1[i][j] * g[9],
                     r0[2*i][2*j], r0[2*i][2*j+1], r0[2*i+1][2*j], r0[2*i+1][2*j+1]);

    float* ob = out + (size_t)b * HH * WW;
    #pragma unroll
    for (int r = 0; r < 8; ++r) {
        float4* row = (float4*)(ob + (size_t)(y0 + r) * WW + x0);
        float4 u0, u1;
        u0.x = r0[r][0]; u0.y = r0[r][1]; u0.z = r0[r][2]; u0.w = r0[r][3];
        u1.x = r0[r][4]; u1.y = r0[r][5]; u1.z = r0[r][6]; u1.w = r0[r][7];
        row[0] = u0; row[1] = u1;
    }
}

extern "C" void kernel_launch(void* const* d_in, const int* in_sizes, int n_in,
                              void* d_out, int out_size, void* d_ws, size_t ws_size,
                              hipStream_t stream) {
    const float* x   = (const float*)d_in[0];
    const float* Wa  = (const float*)d_in[1];
    const float* ba  = (const float*)d_in[2];
    const float* Wd1 = (const float*)d_in[3];
    const float* bd1 = (const float*)d_in[4];
    const float* Wd2 = (const float*)d_in[5];
    const float* bd2 = (const float*)d_in[6];
    const float* Wd3 = (const float*)d_in[7];
    const float* bd3 = (const float*)d_in[8];
    float* out = (float*)d_out;

    const int B = in_sizes[0] / (HH * WW);

    float* partial = (float*)d_ws;                       // [B*64, 10]
    float* gates   = partial + (size_t)B * BLOCKS_PER_B * 10;  // [B, 10]

    dim3 fgrid(8, 8, B);
    wa_fwd_dots<<<fgrid, 256, 0, stream>>>(x, Wa, Wd1, Wd2, Wd3, partial);
    wa_gates<<<B, 64, 0, stream>>>(partial, ba, bd1, bd2, bd3, gates);
    dim3 rgrid(16, 16, B);
    wa_recon<<<rgrid, 64, 0, stream>>>(x, gates, out);
}